// Round 1
// baseline (2696.643 us; speedup 1.0000x reference)
//
#include <hip/hip_runtime.h>
#include <math.h>

#define B    4
#define QL   2048
#define KVL  2048
#define CQ   256
#define CKV  256
#define CH   32
#define NH   8
#define DM   256   // NH*CH

// ---------------------------------------------------------------------------
// Generic fp32 tiled GEMM: out[M,N] = alpha * (X[M,K] @ W[K,N]) (+ bias[N])
// BM=BN=64, BK=16, 256 threads, 4x4 micro-tile per thread.
// ---------------------------------------------------------------------------
__global__ __launch_bounds__(256) void gemm64(
    const float* __restrict__ X, const float* __restrict__ W,
    const float* __restrict__ bias, float* __restrict__ out,
    int M, int N, int K, float alpha)
{
    __shared__ float As[16][65];
    __shared__ float Bs[16][65];

    const int bm = blockIdx.y * 64;
    const int bn = blockIdx.x * 64;
    const int t  = threadIdx.x;
    const int tx = t & 15;       // 16 col groups
    const int ty = t >> 4;       // 16 row groups

    float acc[4][4] = {};

    for (int k0 = 0; k0 < K; k0 += 16) {
        // load A tile: 64 rows x 16 k
        #pragma unroll
        for (int i = 0; i < 4; i++) {
            int e  = t + i * 256;
            int r  = e >> 4;
            int kk = e & 15;
            As[kk][r] = X[(size_t)(bm + r) * K + k0 + kk];
        }
        // load W tile: 16 k x 64 n
        #pragma unroll
        for (int i = 0; i < 4; i++) {
            int e  = t + i * 256;
            int kk = e >> 6;
            int n  = e & 63;
            Bs[kk][n] = W[(size_t)(k0 + kk) * N + bn + n];
        }
        __syncthreads();

        #pragma unroll
        for (int kk = 0; kk < 16; kk++) {
            float a[4], b[4];
            #pragma unroll
            for (int i = 0; i < 4; i++) a[i] = As[kk][ty * 4 + i];
            #pragma unroll
            for (int j = 0; j < 4; j++) b[j] = Bs[kk][tx * 4 + j];
            #pragma unroll
            for (int i = 0; i < 4; i++)
                #pragma unroll
                for (int j = 0; j < 4; j++)
                    acc[i][j] = fmaf(a[i], b[j], acc[i][j]);
        }
        __syncthreads();
    }

    #pragma unroll
    for (int i = 0; i < 4; i++) {
        int r = bm + ty * 4 + i;
        #pragma unroll
        for (int j = 0; j < 4; j++) {
            int n = bn + tx * 4 + j;
            float v = acc[i][j] * alpha;
            if (bias) v += bias[n];
            out[(size_t)r * N + n] = v;
        }
    }
}

// ---------------------------------------------------------------------------
// Attention: one block = (b, h, 16 q-rows). Full S row-block in LDS (fp32),
// exact two-pass softmax, LDS-staged PV.
// grid: (QL/16, NH, B), block 256.
// ---------------------------------------------------------------------------
__global__ __launch_bounds__(256) void attn_kernel(
    const float* __restrict__ qb, const float* __restrict__ kb,
    const float* __restrict__ vb, const float* __restrict__ mask,
    const float* __restrict__ bias, float* __restrict__ ao)
{
    __shared__ float S[16][KVL + 1];   // 131136 B (pad +1 breaks softmax bank conflict)
    __shared__ float qs[16][32];       // 2 KB
    __shared__ float vs[64][32];       // 8 KB
    __shared__ float red[16][17];      // partial reductions

    const int q0 = blockIdx.x * 16;
    const int h  = blockIdx.y;
    const int b  = blockIdx.z;
    const int t  = threadIdx.x;

    // ---- load q tile (16 x 32) ----
    #pragma unroll
    for (int i = 0; i < 2; i++) {
        int e = t + i * 256;
        int r = e >> 5, c = e & 31;
        qs[r][c] = qb[((size_t)b * QL + q0 + r) * DM + h * CH + c];
    }
    __syncthreads();

    const float* kbase = kb + (size_t)b * KVL * DM + h * CH;
    const float* bbase = bias + ((size_t)h * QL + q0) * KVL;
    const float* mbase = mask + (size_t)b * KVL;

    // ---- phase 1: S[r][k] = q.k + maskterm + bias ----
    for (int kc = 0; kc < KVL; kc += 256) {
        const int k = kc + t;
        float kr[32];
        const float4* kp = (const float4*)(kbase + (size_t)k * DM);
        #pragma unroll
        for (int c4 = 0; c4 < 8; c4++) {
            float4 v4 = kp[c4];
            kr[c4 * 4 + 0] = v4.x; kr[c4 * 4 + 1] = v4.y;
            kr[c4 * 4 + 2] = v4.z; kr[c4 * 4 + 3] = v4.w;
        }
        const float mterm = (mbase[k] - 1.0f) * 1e9f;
        #pragma unroll
        for (int r = 0; r < 16; r++) {
            float acc = 0.0f;
            #pragma unroll
            for (int c4 = 0; c4 < 8; c4++) {
                float4 qv = *(const float4*)&qs[r][c4 * 4];
                acc = fmaf(qv.x, kr[c4 * 4 + 0], acc);
                acc = fmaf(qv.y, kr[c4 * 4 + 1], acc);
                acc = fmaf(qv.z, kr[c4 * 4 + 2], acc);
                acc = fmaf(qv.w, kr[c4 * 4 + 3], acc);
            }
            S[r][k] = acc + mterm + bbase[(size_t)r * KVL + k];
        }
    }
    __syncthreads();

    // ---- phase 2: softmax (exact, two-pass; keep P unnormalized, fold 1/sum into PV) ----
    {
        const int r = t & 15, part = t >> 4;   // 16 parts x 128 elements
        float m = -INFINITY;
        #pragma unroll 8
        for (int j = 0; j < 128; j++) m = fmaxf(m, S[r][part * 128 + j]);
        red[r][part] = m;
        __syncthreads();
        if (t < 16) {
            float mm = red[t][0];
            #pragma unroll
            for (int p = 1; p < 16; p++) mm = fmaxf(mm, red[t][p]);
            red[t][16] = mm;
        }
        __syncthreads();
        const float rm = red[r][16];
        float s = 0.0f;
        #pragma unroll 8
        for (int j = 0; j < 128; j++) {
            float p = __expf(S[r][part * 128 + j] - rm);
            S[r][part * 128 + j] = p;
            s += p;
        }
        __syncthreads();   // all reads of red[.][16] done before overwrite
        red[r][part] = s;
        __syncthreads();
        if (t < 16) {
            float ss = 0.0f;
            #pragma unroll
            for (int p = 0; p < 16; p++) ss += red[t][p];
            red[t][16] = 1.0f / ss;
        }
        __syncthreads();
    }

    // ---- phase 3: PV. thread: col c = t&31, row-group rg = t>>5 (rows rg, rg+8) ----
    {
        const int c = t & 31, rg = t >> 5;
        float acc0 = 0.0f, acc1 = 0.0f;
        const float* vbase = vb + (size_t)b * KVL * DM + h * CH;
        for (int kc = 0; kc < KVL; kc += 64) {
            __syncthreads();   // protect vs against previous iteration readers
            #pragma unroll
            for (int i = 0; i < 8; i++) {
                int e  = t + i * 256;
                int rr = e >> 5, cc = e & 31;
                vs[rr][cc] = vbase[(size_t)(kc + rr) * DM + cc];
            }
            __syncthreads();
            #pragma unroll
            for (int kk = 0; kk < 64; kk++) {
                float vv = vs[kk][c];
                acc0 = fmaf(S[rg][kc + kk], vv, acc0);
                acc1 = fmaf(S[rg + 8][kc + kk], vv, acc1);
            }
        }
        const float r0 = red[rg][16], r1 = red[rg + 8][16];
        ao[((size_t)b * QL + q0 + rg) * DM + h * CH + c]     = acc0 * r0;
        ao[((size_t)b * QL + q0 + rg + 8) * DM + h * CH + c] = acc1 * r1;
    }
}

// ---------------------------------------------------------------------------
extern "C" void kernel_launch(void* const* d_in, const int* in_sizes, int n_in,
                              void* d_out, int out_size, void* d_ws, size_t ws_size,
                              hipStream_t stream)
{
    const float* input_q  = (const float*)d_in[0];
    const float* input_kv = (const float*)d_in[1];
    const float* mask     = (const float*)d_in[2];
    const float* bias     = (const float*)d_in[3];
    const float* w_q      = (const float*)d_in[4];
    const float* w_k      = (const float*)d_in[5];
    const float* w_v      = (const float*)d_in[6];
    const float* w_o      = (const float*)d_in[7];
    const float* b_o      = (const float*)d_in[8];
    float* out = (float*)d_out;
    float* ws  = (float*)d_ws;

    const size_t TOK = (size_t)B * QL;        // 8192 token rows
    float* qb = ws;
    float* kb = ws + TOK * DM;
    float* vb = ws + 2 * TOK * DM;
    float* ao = ws + 3 * TOK * DM;

    dim3 blk(256);
    dim3 ggrid(DM / 64, TOK / 64);            // (4, 128)

    const float qscale = 0.17677669529663687f;   // 1/sqrt(32)

    gemm64<<<ggrid, blk, 0, stream>>>(input_q,  w_q, nullptr, qb, (int)TOK, DM, CQ,  qscale);
    gemm64<<<ggrid, blk, 0, stream>>>(input_kv, w_k, nullptr, kb, (int)TOK, DM, CKV, 1.0f);
    gemm64<<<ggrid, blk, 0, stream>>>(input_kv, w_v, nullptr, vb, (int)TOK, DM, CKV, 1.0f);

    attn_kernel<<<dim3(QL / 16, NH, B), blk, 0, stream>>>(qb, kb, vb, mask, bias, ao);

    gemm64<<<ggrid, blk, 0, stream>>>(ao, w_o, b_o, out, (int)TOK, DM, DM, 1.0f);
}

// Round 2
// 230.698 us; speedup vs baseline: 11.6891x; 11.6891x over previous
//
#include <hip/hip_runtime.h>
#include <hip/hip_bf16.h>
#include <math.h>

#define B    4
#define QL   2048
#define KVL  2048
#define CQ   256
#define CKV  256
#define CH   32
#define NH   8
#define DM   256   // NH*CH
#define QB   64    // q rows per block (4 waves x 16)
#define KVB  128   // kv strip per iteration

typedef __attribute__((ext_vector_type(8))) short short8;   // 8 x bf16 (4 VGPR)
typedef __attribute__((ext_vector_type(4))) float f32x4;

static __device__ __forceinline__ short f2bf(float x) {
    __hip_bfloat16 h = __float2bfloat16(x);
    return __builtin_bit_cast(short, h);
}

// ---------------------------------------------------------------------------
// fp32 tiled GEMM, BM=BN=64, BK=16, 256 thr, 4x4 microtile.
// mode 0: fp32 out[m][n] (+bias[n])
// mode 1: bf16 out at [(b*NH+h)*L + l]*32 + c   (head-split, for Q/K)
// mode 2: bf16 out at [(b*NH+h)*32 + c]*L + l   (head-split transposed, for V)
// ---------------------------------------------------------------------------
__global__ __launch_bounds__(256) void gemm64(
    const float* __restrict__ X, const float* __restrict__ W,
    const float* __restrict__ bias, float* __restrict__ outf,
    short* __restrict__ outb,
    int M, int N, int K, float alpha, int mode)
{
    __shared__ float As[16][65];
    __shared__ float Bs[16][65];

    const int bm = blockIdx.y * 64;
    const int bn = blockIdx.x * 64;
    const int t  = threadIdx.x;
    const int tx = t & 15;
    const int ty = t >> 4;

    float acc[4][4] = {};

    for (int k0 = 0; k0 < K; k0 += 16) {
        #pragma unroll
        for (int i = 0; i < 4; i++) {
            int e  = t + i * 256;
            int r  = e >> 4;
            int kk = e & 15;
            As[kk][r] = X[(size_t)(bm + r) * K + k0 + kk];
        }
        #pragma unroll
        for (int i = 0; i < 4; i++) {
            int e  = t + i * 256;
            int kk = e >> 6;
            int n  = e & 63;
            Bs[kk][n] = W[(size_t)(k0 + kk) * N + bn + n];
        }
        __syncthreads();
        #pragma unroll
        for (int kk = 0; kk < 16; kk++) {
            float a[4], b[4];
            #pragma unroll
            for (int i = 0; i < 4; i++) a[i] = As[kk][ty * 4 + i];
            #pragma unroll
            for (int j = 0; j < 4; j++) b[j] = Bs[kk][tx * 4 + j];
            #pragma unroll
            for (int i = 0; i < 4; i++)
                #pragma unroll
                for (int j = 0; j < 4; j++)
                    acc[i][j] = fmaf(a[i], b[j], acc[i][j]);
        }
        __syncthreads();
    }

    #pragma unroll
    for (int i = 0; i < 4; i++) {
        int m = bm + ty * 4 + i;
        #pragma unroll
        for (int j = 0; j < 4; j++) {
            int n = bn + tx * 4 + j;
            float v = acc[i][j] * alpha;
            if (mode == 0) {
                if (bias) v += bias[n];
                outf[(size_t)m * N + n] = v;
            } else {
                int bb = m >> 11, l = m & 2047;
                int hh = n >> 5,  cc = n & 31;
                if (mode == 1)
                    outb[(((size_t)bb * NH + hh) * QL + l) * CH + cc] = f2bf(v);
                else
                    outb[(((size_t)bb * NH + hh) * CH + cc) * (size_t)KVL + l] = f2bf(v);
            }
        }
    }
}

// ---------------------------------------------------------------------------
// Flash attention. Block = (q-tile of 64, h, b), 4 waves; wave w owns 16 rows.
// MFMA 16x16x32 bf16 for QK^T and PV; online softmax in registers.
// Fragment maps (gfx950, m89-verified D layout):
//   A-frag: lane holds A[m=lane&15][k=(lane>>4)*8 + j]
//   B-frag: lane holds B[k=(lane>>4)*8 + j][n=lane&15]
//   D-frag: lane,reg r holds D[row=(lane>>4)*4+r][col=lane&15]
// LDS XOR-swizzle: byte ^= ((row&7)<<4) on both write and read (G4).
// ---------------------------------------------------------------------------
__global__ __launch_bounds__(256) void fattn(
    const short* __restrict__ qbf, const short* __restrict__ kbf,
    const short* __restrict__ vtb, const float* __restrict__ mask,
    const float* __restrict__ bias, float* __restrict__ ao)
{
    __shared__ short Kl[KVB * 32];      // 8 KB, swizzled
    __shared__ short Vl[32 * KVB];      // 8 KB, swizzled (V^T: rows = channel)
    __shared__ short Pl[4][16 * KVB];   // 16 KB, per-wave, swizzled

    const int t    = threadIdx.x;
    const int w    = t >> 6;
    const int lane = t & 63;
    const int c16  = lane & 15;
    const int g    = lane >> 4;

    const int q0 = blockIdx.x * QB;
    const int h  = blockIdx.y, b = blockIdx.z;
    const int bh = b * NH + h;

    // Q fragment (scale folded in projection): row q0+w*16+c16, k = g*8..+7
    short8 qf = *(const short8*)(qbf + ((size_t)bh * QL + q0 + w * 16 + c16) * CH + g * 8);

    f32x4 o0 = {0.f, 0.f, 0.f, 0.f}, o1 = {0.f, 0.f, 0.f, 0.f};
    float m_r[4], l_r[4];
    #pragma unroll
    for (int r = 0; r < 4; r++) { m_r[r] = -INFINITY; l_r[r] = 0.f; }

    const float* bias_base = bias + ((size_t)h * QL + q0 + w * 16) * KVL;
    const float* mask_base = mask + (size_t)b * KVL;
    const short* kg = kbf + (size_t)bh * KVL * CH;
    const short* vg = vtb + (size_t)bh * CH * KVL;
    short* pw = &Pl[w][0];
    const f32x4 zero4 = {0.f, 0.f, 0.f, 0.f};

    #pragma unroll 1
    for (int kv0 = 0; kv0 < KVL; kv0 += KVB) {
        // ---- prefetch bias + mask into registers (coalesced 64B segments) ----
        float bi[8][4], mk[8];
        #pragma unroll
        for (int tt = 0; tt < 8; tt++) {
            mk[tt] = mask_base[kv0 + tt * 16 + c16];
            #pragma unroll
            for (int r = 0; r < 4; r++)
                bi[tt][r] = bias_base[(size_t)(4 * g + r) * KVL + kv0 + tt * 16 + c16];
        }

        __syncthreads();   // prev strip fully consumed
        // ---- stage K tile [128][32] bf16 ----
        #pragma unroll
        for (int i = 0; i < 2; i++) {
            int idx = t + i * 256;
            int row = idx >> 2, ch = idx & 3;
            short8 v = *(const short8*)(kg + (size_t)(kv0 + row) * CH + ch * 8);
            int byte = (row * 64 + ch * 16) ^ ((row & 7) << 4);
            *(short8*)((char*)Kl + byte) = v;
        }
        // ---- stage V^T tile [32][128] bf16 ----
        #pragma unroll
        for (int i = 0; i < 2; i++) {
            int idx = t + i * 256;
            int row = idx >> 4, ch = idx & 15;
            short8 v = *(const short8*)(vg + (size_t)row * KVL + kv0 + ch * 8);
            int byte = (row * 256 + ch * 16) ^ ((row & 7) << 4);
            *(short8*)((char*)Vl + byte) = v;
        }
        __syncthreads();

        // ---- QK^T: 8 subtiles of 16 kv ----
        f32x4 s[8];
        #pragma unroll
        for (int tt = 0; tt < 8; tt++) {
            int row  = tt * 16 + c16;
            int byte = (row * 64 + g * 16) ^ ((row & 7) << 4);
            short8 kf = *(const short8*)((const char*)Kl + byte);
            s[tt] = __builtin_amdgcn_mfma_f32_16x16x32_bf16(qf, kf, zero4, 0, 0, 0);
        }

        // ---- mask + bias + strip row-max ----
        float nm[4];
        #pragma unroll
        for (int r = 0; r < 4; r++) nm[r] = m_r[r];
        #pragma unroll
        for (int tt = 0; tt < 8; tt++) {
            float mt = (mk[tt] - 1.0f) * 1e9f;
            #pragma unroll
            for (int r = 0; r < 4; r++) {
                float sv = s[tt][r] + mt + bi[tt][r];
                s[tt][r] = sv;
                nm[r] = fmaxf(nm[r], sv);
            }
        }
        #pragma unroll
        for (int r = 0; r < 4; r++) {
            #pragma unroll
            for (int off = 1; off < 16; off <<= 1)
                nm[r] = fmaxf(nm[r], __shfl_xor(nm[r], off));
        }

        // ---- online rescale ----
        #pragma unroll
        for (int r = 0; r < 4; r++) {
            float sc = __expf(m_r[r] - nm[r]);   // -inf init -> 0, nm always finite
            m_r[r] = nm[r];
            l_r[r] *= sc;
            o0[r] *= sc;  o1[r] *= sc;
        }

        // ---- p = exp(s-m), per-lane partial sum, write P (bf16) to wave LDS ----
        #pragma unroll
        for (int tt = 0; tt < 8; tt++) {
            #pragma unroll
            for (int r = 0; r < 4; r++) {
                float p = __expf(s[tt][r] - m_r[r]);
                l_r[r] += p;
                int q    = 4 * g + r;
                int byte = (q * 256 + (tt * 16 + c16) * 2) ^ ((q & 7) << 4);
                *(short*)((char*)pw + byte) = f2bf(p);
            }
        }

        // ---- PV: O[16q][32c] += P[16][128] @ V[128][32], 4 K-chunks x 2 N ----
        #pragma unroll
        for (int kk = 0; kk < 4; kk++) {
            int pb  = (c16 * 256 + (kk * 32 + g * 8) * 2) ^ ((c16 & 7) << 4);
            short8 pf  = *(const short8*)((const char*)pw + pb);
            int v0b = (c16 * 256 + (kk * 32 + g * 8) * 2) ^ ((c16 & 7) << 4);
            short8 vf0 = *(const short8*)((const char*)Vl + v0b);
            int v1b = ((16 + c16) * 256 + (kk * 32 + g * 8) * 2) ^ ((c16 & 7) << 4);
            short8 vf1 = *(const short8*)((const char*)Vl + v1b);
            o0 = __builtin_amdgcn_mfma_f32_16x16x32_bf16(pf, vf0, o0, 0, 0, 0);
            o1 = __builtin_amdgcn_mfma_f32_16x16x32_bf16(pf, vf1, o1, 0, 0, 0);
        }
    }

    // ---- finalize: reduce row-sums across the 16-lane group, write O ----
    #pragma unroll
    for (int r = 0; r < 4; r++) {
        #pragma unroll
        for (int off = 1; off < 16; off <<= 1)
            l_r[r] += __shfl_xor(l_r[r], off);
    }
    float* aop = ao + ((size_t)b * QL + q0 + w * 16) * DM + h * CH;
    #pragma unroll
    for (int r = 0; r < 4; r++) {
        float inv = 1.0f / l_r[r];
        int q = 4 * g + r;
        aop[(size_t)q * DM + c16]      = o0[r] * inv;
        aop[(size_t)q * DM + 16 + c16] = o1[r] * inv;
    }
}

// ---------------------------------------------------------------------------
extern "C" void kernel_launch(void* const* d_in, const int* in_sizes, int n_in,
                              void* d_out, int out_size, void* d_ws, size_t ws_size,
                              hipStream_t stream)
{
    const float* input_q  = (const float*)d_in[0];
    const float* input_kv = (const float*)d_in[1];
    const float* mask     = (const float*)d_in[2];
    const float* bias     = (const float*)d_in[3];
    const float* w_q      = (const float*)d_in[4];
    const float* w_k      = (const float*)d_in[5];
    const float* w_v      = (const float*)d_in[6];
    const float* w_o      = (const float*)d_in[7];
    const float* b_o      = (const float*)d_in[8];
    float* out = (float*)d_out;

    const size_t TOK  = (size_t)B * QL;          // 8192
    const size_t HEAD = (size_t)B * NH * QL * CH; // 2,097,152 elems

    short* qbf = (short*)d_ws;
    short* kbf = qbf + HEAD;
    short* vtb = kbf + HEAD;
    float* ao  = (float*)(vtb + HEAD);           // 12 MB offset, aligned

    dim3 blk(256);
    dim3 ggrid(DM / 64, TOK / 64);               // (4, 128)
    const float qscale = 0.17677669529663687f;   // 1/sqrt(32)

    gemm64<<<ggrid, blk, 0, stream>>>(input_q,  w_q, nullptr, nullptr, qbf,
                                      (int)TOK, DM, CQ,  qscale, 1);
    gemm64<<<ggrid, blk, 0, stream>>>(input_kv, w_k, nullptr, nullptr, kbf,
                                      (int)TOK, DM, CKV, 1.0f, 1);
    gemm64<<<ggrid, blk, 0, stream>>>(input_kv, w_v, nullptr, nullptr, vtb,
                                      (int)TOK, DM, CKV, 1.0f, 2);

    fattn<<<dim3(QL / QB, NH, B), blk, 0, stream>>>(qbf, kbf, vtb, mask, bias, ao);

    gemm64<<<dim3(CQ / 64, TOK / 64), blk, 0, stream>>>(ao, w_o, b_o, out, nullptr,
                                      (int)TOK, CQ, DM, 1.0f, 0);
}

// Round 3
// 148.038 us; speedup vs baseline: 18.2158x; 1.5584x over previous
//
#include <hip/hip_runtime.h>
#include <hip/hip_bf16.h>
#include <math.h>

#define B    4
#define QL   2048
#define KVL  2048
#define CQ   256
#define CKV  256
#define CH   32
#define NH   8
#define DM   256   // NH*CH
#define QB   64    // q rows per fattn block (4 waves x 16)
#define KVB  128   // kv strip per iteration

typedef __attribute__((ext_vector_type(8))) short short8;   // 8 x bf16 (4 VGPR)
typedef __attribute__((ext_vector_type(4))) float f32x4;

static __device__ __forceinline__ short f2bf(float x) {
    __hip_bfloat16 h = __float2bfloat16(x);
    return __builtin_bit_cast(short, h);
}

// ---------------------------------------------------------------------------
// prep: fp32 -> bf16 copy (8 elems/thread)
// ---------------------------------------------------------------------------
__global__ __launch_bounds__(256) void prep_cvt(
    const float* __restrict__ src, short* __restrict__ dst, int n8)
{
    int i = blockIdx.x * 256 + threadIdx.x;
    if (i >= n8) return;
    const float4* s = (const float4*)src + (size_t)i * 2;
    float4 a = s[0], b = s[1];
    short8 o = { f2bf(a.x), f2bf(a.y), f2bf(a.z), f2bf(a.w),
                 f2bf(b.x), f2bf(b.y), f2bf(b.z), f2bf(b.w) };
    *((short8*)dst + i) = o;
}

// ---------------------------------------------------------------------------
// prep: W [K][N] fp32 -> W^T [N][K] bf16, 32x32 LDS tiles
// ---------------------------------------------------------------------------
__global__ __launch_bounds__(256) void prep_wT(
    const float* __restrict__ w, short* __restrict__ wt, int K, int N)
{
    __shared__ float tile[32][33];
    const int bx = blockIdx.x * 32;            // n
    const int by = blockIdx.y * 32;            // k
    const int tx = threadIdx.x & 31, ty = threadIdx.x >> 5;
    #pragma unroll
    for (int i = 0; i < 32; i += 8)
        tile[ty + i][tx] = w[(size_t)(by + ty + i) * N + bx + tx];
    __syncthreads();
    #pragma unroll
    for (int i = 0; i < 32; i += 8)
        wt[(size_t)(bx + ty + i) * K + by + tx] = f2bf(tile[tx][ty + i]);
}

// ---------------------------------------------------------------------------
// bf16 MFMA GEMM: A [M][K] bf16 row-major, BT [N][K] bf16 row-major.
// 64x64 tile, 4 waves (2x2 of 32x32), BK=32 (one 16x16x32 MFMA K-step).
// LDS rows padded to 40 shorts (80 B) -> 2-way bank aliasing only (free, m136).
// mode 0: fp32 out[m][n] + bias[n]
// mode 1: bf16 out at [(b*NH+h)*QL + l]*32 + c   (head-split, Q/K)
// mode 2: bf16 out at [(b*NH+h)*32 + c]*KVL + l  (head-split transposed, V)
// Fragment maps (m89-verified): A-frag lane: A[m=lane&15][k=(lane>>4)*8+j];
// B-frag lane: B[k=(lane>>4)*8+j][n=lane&15] = BT[n][k]; D: row=(lane>>4)*4+r, col=lane&15.
// ---------------------------------------------------------------------------
__global__ __launch_bounds__(256) void gemm_mfma(
    const short* __restrict__ A, const short* __restrict__ BT,
    const float* __restrict__ bias, float* __restrict__ outf,
    short* __restrict__ outb,
    int M, int N, int K, float alpha, int mode)
{
    __shared__ __align__(16) short As[64][40];
    __shared__ __align__(16) short Bs[64][40];

    const int t   = threadIdx.x;
    const int m0  = blockIdx.y * 64, n0 = blockIdx.x * 64;
    const int lane = t & 63, w = t >> 6;
    const int c16 = lane & 15, g = lane >> 4;
    const int wm  = (w & 1) * 32, wn = (w >> 1) * 32;
    const int lr  = t >> 2, lc = (t & 3) * 8;   // staging row / col(8-chunk)

    f32x4 acc[2][2] = {};

    for (int k0 = 0; k0 < K; k0 += 32) {
        __syncthreads();
        *(short8*)&As[lr][lc] = *(const short8*)(A  + (size_t)(m0 + lr) * K + k0 + lc);
        *(short8*)&Bs[lr][lc] = *(const short8*)(BT + (size_t)(n0 + lr) * K + k0 + lc);
        __syncthreads();

        short8 af[2], bf[2];
        #pragma unroll
        for (int i = 0; i < 2; i++) {
            af[i] = *(const short8*)&As[wm + i * 16 + c16][g * 8];
            bf[i] = *(const short8*)&Bs[wn + i * 16 + c16][g * 8];
        }
        #pragma unroll
        for (int i = 0; i < 2; i++)
            #pragma unroll
            for (int j = 0; j < 2; j++)
                acc[i][j] = __builtin_amdgcn_mfma_f32_16x16x32_bf16(af[i], bf[j], acc[i][j], 0, 0, 0);
    }

    #pragma unroll
    for (int i = 0; i < 2; i++) {
        #pragma unroll
        for (int j = 0; j < 2; j++) {
            #pragma unroll
            for (int r = 0; r < 4; r++) {
                int m = m0 + wm + i * 16 + g * 4 + r;
                int n = n0 + wn + j * 16 + c16;
                float v = acc[i][j][r] * alpha;
                if (mode == 0) {
                    outf[(size_t)m * N + n] = v + (bias ? bias[n] : 0.0f);
                } else {
                    int bb = m >> 11, l = m & 2047;   // QL = 2048
                    int hh = n >> 5,  cc = n & 31;
                    if (mode == 1)
                        outb[(((size_t)bb * NH + hh) * QL + l) * CH + cc] = f2bf(v);
                    else
                        outb[(((size_t)bb * NH + hh) * CH + cc) * (size_t)KVL + l] = f2bf(v);
                }
            }
        }
    }
}

// ---------------------------------------------------------------------------
// Flash attention (unchanged structure from R2; output now bf16).
// Block = (q-tile 64, h, b), 4 waves; wave owns 16 q rows.
// ---------------------------------------------------------------------------
__global__ __launch_bounds__(256) void fattn(
    const short* __restrict__ qbf, const short* __restrict__ kbf,
    const short* __restrict__ vtb, const float* __restrict__ mask,
    const float* __restrict__ bias, short* __restrict__ aob)
{
    __shared__ short Kl[KVB * 32];      // 8 KB, swizzled
    __shared__ short Vl[32 * KVB];      // 8 KB, swizzled (V^T rows = channel)
    __shared__ short Pl[4][16 * KVB];   // 16 KB, per-wave, swizzled

    const int t    = threadIdx.x;
    const int w    = t >> 6;
    const int lane = t & 63;
    const int c16  = lane & 15;
    const int g    = lane >> 4;

    const int q0 = blockIdx.x * QB;
    const int h  = blockIdx.y, b = blockIdx.z;
    const int bh = b * NH + h;

    short8 qf = *(const short8*)(qbf + ((size_t)bh * QL + q0 + w * 16 + c16) * CH + g * 8);

    f32x4 o0 = {0.f, 0.f, 0.f, 0.f}, o1 = {0.f, 0.f, 0.f, 0.f};
    float m_r[4], l_r[4];
    #pragma unroll
    for (int r = 0; r < 4; r++) { m_r[r] = -INFINITY; l_r[r] = 0.f; }

    const float* bias_base = bias + ((size_t)h * QL + q0 + w * 16) * KVL;
    const float* mask_base = mask + (size_t)b * KVL;
    const short* kg = kbf + (size_t)bh * KVL * CH;
    const short* vg = vtb + (size_t)bh * CH * KVL;
    short* pw = &Pl[w][0];
    const f32x4 zero4 = {0.f, 0.f, 0.f, 0.f};

    #pragma unroll 1
    for (int kv0 = 0; kv0 < KVL; kv0 += KVB) {
        float bi[8][4], mk[8];
        #pragma unroll
        for (int tt = 0; tt < 8; tt++) {
            mk[tt] = mask_base[kv0 + tt * 16 + c16];
            #pragma unroll
            for (int r = 0; r < 4; r++)
                bi[tt][r] = bias_base[(size_t)(4 * g + r) * KVL + kv0 + tt * 16 + c16];
        }

        __syncthreads();
        #pragma unroll
        for (int i = 0; i < 2; i++) {
            int idx = t + i * 256;
            int row = idx >> 2, ch = idx & 3;
            short8 v = *(const short8*)(kg + (size_t)(kv0 + row) * CH + ch * 8);
            int byte = (row * 64 + ch * 16) ^ ((row & 7) << 4);
            *(short8*)((char*)Kl + byte) = v;
        }
        #pragma unroll
        for (int i = 0; i < 2; i++) {
            int idx = t + i * 256;
            int row = idx >> 4, ch = idx & 15;
            short8 v = *(const short8*)(vg + (size_t)row * KVL + kv0 + ch * 8);
            int byte = (row * 256 + ch * 16) ^ ((row & 7) << 4);
            *(short8*)((char*)Vl + byte) = v;
        }
        __syncthreads();

        f32x4 s[8];
        #pragma unroll
        for (int tt = 0; tt < 8; tt++) {
            int row  = tt * 16 + c16;
            int byte = (row * 64 + g * 16) ^ ((row & 7) << 4);
            short8 kf = *(const short8*)((const char*)Kl + byte);
            s[tt] = __builtin_amdgcn_mfma_f32_16x16x32_bf16(qf, kf, zero4, 0, 0, 0);
        }

        float nm[4];
        #pragma unroll
        for (int r = 0; r < 4; r++) nm[r] = m_r[r];
        #pragma unroll
        for (int tt = 0; tt < 8; tt++) {
            float mt = (mk[tt] - 1.0f) * 1e9f;
            #pragma unroll
            for (int r = 0; r < 4; r++) {
                float sv = s[tt][r] + mt + bi[tt][r];
                s[tt][r] = sv;
                nm[r] = fmaxf(nm[r], sv);
            }
        }
        #pragma unroll
        for (int r = 0; r < 4; r++) {
            #pragma unroll
            for (int off = 1; off < 16; off <<= 1)
                nm[r] = fmaxf(nm[r], __shfl_xor(nm[r], off));
        }

        #pragma unroll
        for (int r = 0; r < 4; r++) {
            float sc = __expf(m_r[r] - nm[r]);
            m_r[r] = nm[r];
            l_r[r] *= sc;
            o0[r] *= sc;  o1[r] *= sc;
        }

        #pragma unroll
        for (int tt = 0; tt < 8; tt++) {
            #pragma unroll
            for (int r = 0; r < 4; r++) {
                float p = __expf(s[tt][r] - m_r[r]);
                l_r[r] += p;
                int q    = 4 * g + r;
                int byte = (q * 256 + (tt * 16 + c16) * 2) ^ ((q & 7) << 4);
                *(short*)((char*)pw + byte) = f2bf(p);
            }
        }

        #pragma unroll
        for (int kk = 0; kk < 4; kk++) {
            int pb  = (c16 * 256 + (kk * 32 + g * 8) * 2) ^ ((c16 & 7) << 4);
            short8 pf  = *(const short8*)((const char*)pw + pb);
            int v0b = (c16 * 256 + (kk * 32 + g * 8) * 2) ^ ((c16 & 7) << 4);
            short8 vf0 = *(const short8*)((const char*)Vl + v0b);
            int v1b = ((16 + c16) * 256 + (kk * 32 + g * 8) * 2) ^ ((c16 & 7) << 4);
            short8 vf1 = *(const short8*)((const char*)Vl + v1b);
            o0 = __builtin_amdgcn_mfma_f32_16x16x32_bf16(pf, vf0, o0, 0, 0, 0);
            o1 = __builtin_amdgcn_mfma_f32_16x16x32_bf16(pf, vf1, o1, 0, 0, 0);
        }
    }

    #pragma unroll
    for (int r = 0; r < 4; r++) {
        #pragma unroll
        for (int off = 1; off < 16; off <<= 1)
            l_r[r] += __shfl_xor(l_r[r], off);
    }
    short* aop = aob + ((size_t)b * QL + q0 + w * 16) * DM + h * CH;
    #pragma unroll
    for (int r = 0; r < 4; r++) {
        float inv = 1.0f / l_r[r];
        int q = 4 * g + r;
        aop[(size_t)q * DM + c16]      = f2bf(o0[r] * inv);
        aop[(size_t)q * DM + 16 + c16] = f2bf(o1[r] * inv);
    }
}

// ---------------------------------------------------------------------------
extern "C" void kernel_launch(void* const* d_in, const int* in_sizes, int n_in,
                              void* d_out, int out_size, void* d_ws, size_t ws_size,
                              hipStream_t stream)
{
    const float* input_q  = (const float*)d_in[0];
    const float* input_kv = (const float*)d_in[1];
    const float* mask     = (const float*)d_in[2];
    const float* bias     = (const float*)d_in[3];
    const float* w_q      = (const float*)d_in[4];
    const float* w_k      = (const float*)d_in[5];
    const float* w_v      = (const float*)d_in[6];
    const float* w_o      = (const float*)d_in[7];
    const float* b_o      = (const float*)d_in[8];
    float* out = (float*)d_out;

    const size_t TOK  = (size_t)B * QL;            // 8192
    const size_t HEAD = (size_t)B * NH * QL * CH;  // 2,097,152 elems

    short* qbf = (short*)d_ws;          // bf16 Q  head-split       4 MB
    short* kbf = qbf + HEAD;            // bf16 K  head-split       4 MB
    short* vtb = kbf + HEAD;            // bf16 V^T head-split      4 MB
    short* aob = vtb + HEAD;            // bf16 attn out [tok][dm]  4 MB
    short* qx  = aob + HEAD;            // bf16 input_q             4 MB
    short* kvx = qx  + HEAD;            // bf16 input_kv            4 MB
    short* wqT = kvx + HEAD;            // bf16 w_q^T  [N][K]       128 KB
    short* wkT = wqT + CQ * DM;
    short* wvT = wkT + CKV * DM;
    short* woT = wvT + CKV * DM;

    dim3 blk(256);
    const float qscale = 0.17677669529663687f;     // 1/sqrt(32)

    // prep: inputs -> bf16 ; weights -> transposed bf16
    prep_cvt<<<dim3((TOK * CQ / 8 + 255) / 256), blk, 0, stream>>>(input_q,  qx,  (int)(TOK * CQ / 8));
    prep_cvt<<<dim3((TOK * CKV / 8 + 255) / 256), blk, 0, stream>>>(input_kv, kvx, (int)(TOK * CKV / 8));
    prep_wT<<<dim3(DM / 32, CQ / 32),  blk, 0, stream>>>(w_q, wqT, CQ,  DM);
    prep_wT<<<dim3(DM / 32, CKV / 32), blk, 0, stream>>>(w_k, wkT, CKV, DM);
    prep_wT<<<dim3(DM / 32, CKV / 32), blk, 0, stream>>>(w_v, wvT, CKV, DM);
    prep_wT<<<dim3(CQ / 32, DM / 32),  blk, 0, stream>>>(w_o, woT, DM,  CQ);

    dim3 pgrid(DM / 64, TOK / 64);                 // (4, 128)
    gemm_mfma<<<pgrid, blk, 0, stream>>>(qx,  wqT, nullptr, nullptr, qbf,
                                         (int)TOK, DM, CQ,  qscale, 1);
    gemm_mfma<<<pgrid, blk, 0, stream>>>(kvx, wkT, nullptr, nullptr, kbf,
                                         (int)TOK, DM, CKV, 1.0f, 1);
    gemm_mfma<<<pgrid, blk, 0, stream>>>(kvx, wvT, nullptr, nullptr, vtb,
                                         (int)TOK, DM, CKV, 1.0f, 2);

    fattn<<<dim3(QL / QB, NH, B), blk, 0, stream>>>(qbf, kbf, vtb, mask, bias, aob);

    gemm_mfma<<<dim3(CQ / 64, TOK / 64), blk, 0, stream>>>(aob, woT, b_o, out, nullptr,
                                         (int)TOK, CQ, DM, 1.0f, 0);
}